// Round 15
// baseline (427.922 us; speedup 1.0000x reference)
//
#include <hip/hip_runtime.h>
#include <hip/hip_bf16.h>

#define NPTS 32768      // B*N
#define NPC  8192       // N per cloud
#define KNN  16
#define CH   64
#define FDIM 128
#define EMPTYKEY 0x7F7FFFFFu

typedef __bf16 bf16;
typedef __bf16 bf16x2 __attribute__((ext_vector_type(2)));
typedef __bf16 bf16x8 __attribute__((ext_vector_type(8)));
typedef float  f32x4  __attribute__((ext_vector_type(4)));

// ---------------- Kernel 0: pre-pack candidates (x,y,z, -0.5|p|^2) ----------------
__global__ __launch_bounds__(256) void k_prew(
    const float* __restrict__ pos, float4* __restrict__ posW)
{
    int i = blockIdx.x * 256 + threadIdx.x;
    float x = pos[i*3+0], y = pos[i*3+1], z = pos[i*3+2];
    float w = -0.5f * fmaf(x, x, fmaf(y, y, z*z));
    posW[i] = make_float4(x, y, z, w);
}

// ---------------- Kernel 1: encode (F->C) + q/k/v (C->C), bf16 outputs ----------------
__global__ __launch_bounds__(256) void k_encode(
    const float* __restrict__ feat,
    const float* __restrict__ Wenc, const float* __restrict__ benc,
    const float* __restrict__ Wq, const float* __restrict__ bq,
    const float* __restrict__ Wk, const float* __restrict__ bk,
    const float* __restrict__ Wv, const float* __restrict__ bv,
    bf16* __restrict__ qo, bf16* __restrict__ kvo)
{
    __shared__ float xs[4][CH];
    int t = threadIdx.x;
    int c = t & 63, pl = t >> 6;
    size_t pt = (size_t)blockIdx.x * 4 + pl;
    const float* fr = feat + pt * FDIM;
    float acc = benc[c];
#pragma unroll 8
    for (int f4 = 0; f4 < 32; ++f4) {
        float4 fv = *reinterpret_cast<const float4*>(fr + f4 * 4);
        acc += fv.x * Wenc[(f4*4+0)*CH + c];
        acc += fv.y * Wenc[(f4*4+1)*CH + c];
        acc += fv.z * Wenc[(f4*4+2)*CH + c];
        acc += fv.w * Wenc[(f4*4+3)*CH + c];
    }
    xs[pl][c] = acc;
    __syncthreads();
    float aq = bq[c], ak = bk[c], av = bv[c];
#pragma unroll 4
    for (int m = 0; m < CH; ++m) {
        float xm = xs[pl][m];
        aq += xm * Wq[m*CH + c];
        ak += xm * Wk[m*CH + c];
        av += xm * Wv[m*CH + c];
    }
    qo[pt*CH + c] = (bf16)aq;
    bf16x2 kv2; kv2[0] = (bf16)ak; kv2[1] = (bf16)av;
    *reinterpret_cast<bf16x2*>(&kvo[pt*2*CH + 2*c]) = kv2;
}

// ---------------- Kernel 2: exact kNN, slice-parallel, scalar-pipe scan ----------------
// Candidates read from global posW with WAVE-UNIFORM addresses -> compiler
// scalarizes to s_load (SMEM pipe, parallel to VALU). No LDS staging, no
// stage-sync; LDS holds only append buffers. Scan/key/drain math byte-
// identical to R14 (bit-identical output).
__global__ __launch_bounds__(256, 4) void k_knn(
    const float4* __restrict__ posW, const float* __restrict__ pos,
    unsigned* __restrict__ wsK)
{
    __shared__ unsigned sbuf[256 * 21];  // 21 KB append buffers

    int t = threadIdx.x;
    int blk = blockIdx.x;
    int slice = blk & 7;
    int qg = (blk >> 3) & 31;
    int cloud = blk >> 8;
    const float* pc = pos + (size_t)cloud * NPC * 3;
    const float4* pw = posW + (size_t)cloud * NPC + (slice << 10);  // uniform base
    int jbase = slice << 10;

    int qi = (qg << 8) + t;
    float myx = pc[qi*3+0], myy = pc[qi*3+1], myz = pc[qi*3+2];
    float qq = fmaf(myx, myx, fmaf(myy, myy, myz*myz));

    unsigned arr[16];
#pragma unroll
    for (int r = 0; r < 16; ++r) arr[r] = EMPTYKEY;
    float thrf = __uint_as_float(EMPTYKEY & 0xFFFFE000u);
    float sthr = (qq - thrf) * 0.5f;     // very negative -> all hit initially
    int cnt = 0;
    int base = t * 21;

    for (int g = 0; g < 1024; g += 8) {
        float sv[8];
#pragma unroll
        for (int u = 0; u < 8; ++u) {
            float4 p = pw[g + u];        // uniform addr -> s_load
            sv[u] = fmaf(myx, p.x, fmaf(myy, p.y, fmaf(myz, p.z, p.w)));
        }
        float m8 = fmaxf(fmaxf(fmaxf(sv[0], sv[1]), fmaxf(sv[2], sv[3])),
                         fmaxf(fmaxf(sv[4], sv[5]), fmaxf(sv[6], sv[7])));
        if (__any(m8 >= sthr)) {
#pragma unroll
            for (int u = 0; u < 8; ++u) {
                if (sv[u] >= sthr) {
                    float d2 = fmaxf(fmaf(-2.f, sv[u], qq), 0.f);
                    sbuf[base + cnt] = (__float_as_uint(d2) & 0xFFFFE000u)
                                       | (unsigned)(jbase + g + u);
                    ++cnt;
                }
            }
            if (__any(cnt >= 13)) {
#pragma unroll
                for (int b = 0; b < 20; ++b) {
                    unsigned key = (b < cnt) ? sbuf[base + b] : EMPTYKEY;
                    if (key < arr[15]) {        // prefilter (ties can't enter)
#pragma unroll
                        for (int r = 0; r < 16; ++r) {
                            unsigned lo = min(key, arr[r]);
                            unsigned hi = max(key, arr[r]);
                            arr[r] = lo; key = hi;
                        }
                    }
                }
                cnt = 0;
                thrf = __uint_as_float(arr[15] & 0xFFFFE000u);
                sthr = (qq - thrf) * 0.5f;
            }
        }
    }
#pragma unroll
    for (int b = 0; b < 20; ++b) {
        unsigned key = (b < cnt) ? sbuf[base + b] : EMPTYKEY;
        if (key < arr[15]) {
#pragma unroll
            for (int r = 0; r < 16; ++r) {
                unsigned lo = min(key, arr[r]);
                unsigned hi = max(key, arr[r]);
                arr[r] = lo; key = hi;
            }
        }
    }
    size_t gq = (size_t)cloud * NPC + qi;
#pragma unroll
    for (int r = 0; r < 16; ++r) wsK[(size_t)(slice*16 + r)*NPTS + gq] = arr[r];
}

// ---------------- Kernel 2b: merge 8 sorted 16-lists + pack weights ----------------
__global__ __launch_bounds__(64) void k_merge(
    const unsigned* __restrict__ wsK, int* __restrict__ idxout,
    const float* __restrict__ Wp2, const float* __restrict__ Wa1,
    const float* __restrict__ Wa2, bf16* __restrict__ wpk)
{
    __shared__ unsigned kk[64][137];   // 8 lists x (16 keys + sentinel)
    int t = threadIdx.x;
    size_t q = (size_t)blockIdx.x * 64 + t;
#pragma unroll
    for (int l = 0; l < 8; ++l) {
#pragma unroll
        for (int r = 0; r < 16; ++r)
            kk[t][l*17 + r] = wsK[(size_t)(l*16 + r)*NPTS + q];   // coalesced
        kk[t][l*17 + 16] = 0xFFFFFFFFu;
    }

    unsigned h0=0,h1=0,h2=0,h3=0,h4=0,h5=0,h6=0,h7=0;
    int* o = idxout + q * KNN;
    for (int r = 0; r < KNN; ++r) {
        unsigned best = 0xFFFFFFFFu; int bl = 0; unsigned k;
        k = kk[t][0*17 + h0]; if (k < best) { best = k; bl = 0; }
        k = kk[t][1*17 + h1]; if (k < best) { best = k; bl = 1; }
        k = kk[t][2*17 + h2]; if (k < best) { best = k; bl = 2; }
        k = kk[t][3*17 + h3]; if (k < best) { best = k; bl = 3; }
        k = kk[t][4*17 + h4]; if (k < best) { best = k; bl = 4; }
        k = kk[t][5*17 + h5]; if (k < best) { best = k; bl = 5; }
        k = kk[t][6*17 + h6]; if (k < best) { best = k; bl = 6; }
        k = kk[t][7*17 + h7]; if (k < best) { best = k; bl = 7; }
        o[r] = (int)(best & 0x1FFFu);
        h0 += (bl == 0); h1 += (bl == 1); h2 += (bl == 2); h3 += (bl == 3);
        h4 += (bl == 4); h5 += (bl == 5); h6 += (bl == 6); h7 += (bl == 7);
    }

    if (blockIdx.x == 0) {
        int lane = t;
        int mlane = lane & 15, kgrp = lane >> 4;
        const float* Ws[3] = {Wp2, Wa1, Wa2};
        bf16x8* ow = reinterpret_cast<bf16x8*>(wpk);
        for (int gmm = 0; gmm < 3; ++gmm) {
#pragma unroll
            for (int nt = 0; nt < 4; ++nt) {
#pragma unroll
                for (int kt = 0; kt < 2; ++kt) {
                    bf16x8 v;
#pragma unroll
                    for (int j = 0; j < 8; ++j)
                        v[j] = (bf16)Ws[gmm][(kt*32 + kgrp*8 + j)*CH + nt*16 + mlane];
                    ow[(gmm*8 + nt*2 + kt)*64 + lane] = v;
                }
            }
        }
    }
}

// ---------------- Kernel 3: MFMA fused neighbor MLPs + vector attention ----------------
__device__ __forceinline__ void wave_gemm(
    const bf16* At, f32x4 (&acc)[4][4], const bf16x8* __restrict__ wpk,
    int w, int lane)
{
    int kgrp = lane >> 4;
    bf16x8 wf[4][2];
#pragma unroll
    for (int nt = 0; nt < 4; ++nt)
#pragma unroll
        for (int kt = 0; kt < 2; ++kt)
            wf[nt][kt] = wpk[(nt*2 + kt)*64 + lane];
#pragma unroll
    for (int mt = 0; mt < 4; ++mt) {
        int row = w*64 + mt*16 + (lane & 15);
        const bf16* rb = At + row*CH;
        int sw = row & 7;
        bf16x8 a0 = *reinterpret_cast<const bf16x8*>(rb + ((kgrp     ^ sw) * 8));
        bf16x8 a1 = *reinterpret_cast<const bf16x8*>(rb + (((4+kgrp) ^ sw) * 8));
#pragma unroll
        for (int nt = 0; nt < 4; ++nt) {
            acc[mt][nt] = __builtin_amdgcn_mfma_f32_16x16x32_bf16(a0, wf[nt][0], acc[mt][nt], 0, 0, 0);
            acc[mt][nt] = __builtin_amdgcn_mfma_f32_16x16x32_bf16(a1, wf[nt][1], acc[mt][nt], 0, 0, 0);
        }
    }
}

// (128,6): occupancy ceiling (R11 win). Epilogue batches all 16 kv-gather
// dwords per mt into registers before any dependent compute.
__global__ __launch_bounds__(128, 6) void k_attn(
    const float* __restrict__ pos, const int* __restrict__ nidx,
    const bf16* __restrict__ qg, const bf16* __restrict__ kvg,
    const float* __restrict__ Wp1, const float* __restrict__ bp1,
    const float* __restrict__ bp2, const float* __restrict__ ba1,
    const float* __restrict__ ba2, const bf16* __restrict__ wpkg,
    float* __restrict__ yout)
{
    __shared__ bf16 At[128 * CH];   // 16 KB (h1 -> a0 -> h2)

    int t = threadIdx.x;
    int w = t >> 6, lane = t & 63;
    int mlane = lane & 15, kgrp = lane >> 4;
    int blk = blockIdx.x;
    int xcd = blk & 7;
    int cloud = xcd >> 1;
    int sub = ((blk >> 3) << 1) | (xcd & 1);        // [0,1024) within cloud
    size_t cbase = (size_t)cloud * NPC;
    size_t p0 = cbase + (size_t)sub * 8;
    const bf16x2* kv2 = reinterpret_cast<const bf16x2*>(kvg);
    const bf16x8* wpk = reinterpret_cast<const bf16x8*>(wpkg);

    {
        int p = t >> 4, j = t & 15;
        size_t gp = p0 + p;
        int nbr = nidx[gp*KNN + j];
        size_t gn = cbase + (size_t)nbr;
        float rx = pos[gp*3+0] - pos[gn*3+0];
        float ry = pos[gp*3+1] - pos[gn*3+1];
        float rz = pos[gp*3+2] - pos[gn*3+2];
        float h[CH];
#pragma unroll
        for (int c4 = 0; c4 < 16; ++c4) {
            float4 w0 = *reinterpret_cast<const float4*>(Wp1 + 0*CH + c4*4);
            float4 w1 = *reinterpret_cast<const float4*>(Wp1 + 1*CH + c4*4);
            float4 w2 = *reinterpret_cast<const float4*>(Wp1 + 2*CH + c4*4);
            float4 bb = *reinterpret_cast<const float4*>(bp1 + c4*4);
            h[c4*4+0] = fmaxf(rx*w0.x + ry*w1.x + rz*w2.x + bb.x, 0.f);
            h[c4*4+1] = fmaxf(rx*w0.y + ry*w1.y + rz*w2.y + bb.y, 0.f);
            h[c4*4+2] = fmaxf(rx*w0.z + ry*w1.z + rz*w2.z + bb.z, 0.f);
            h[c4*4+3] = fmaxf(rx*w0.w + ry*w1.w + rz*w2.w + bb.w, 0.f);
        }
#pragma unroll
        for (int ch = 0; ch < 8; ++ch) {
            bf16x8 v;
#pragma unroll
            for (int e = 0; e < 8; ++e) v[e] = (bf16)h[ch*8 + e];
            *reinterpret_cast<bf16x8*>(&At[t*CH + (ch ^ (t & 7)) * 8]) = v;
        }
    }

    f32x4 acc[4][4];

    // ---- GEMM2: delta = h1 @ Wp2 + bp2 ----
#pragma unroll
    for (int nt = 0; nt < 4; ++nt) {
        float b = bp2[nt*16 + mlane];
#pragma unroll
        for (int mt = 0; mt < 4; ++mt) { acc[mt][nt][0]=b; acc[mt][nt][1]=b; acc[mt][nt][2]=b; acc[mt][nt][3]=b; }
    }
    wave_gemm(At, acc, wpk, w, lane);

    // ---- epilogue: a0 = q-k+delta -> At ; vd = v+delta -> packed regs ----
    bf16x2 vdp[4][4][2];
#pragma unroll
    for (int mt = 0; mt < 4; ++mt) {
        size_t gp = p0 + (size_t)(w*4 + mt);
        int nb[4];
#pragma unroll
        for (int reg = 0; reg < 4; ++reg)
            nb[reg] = nidx[gp*KNN + kgrp*4 + reg];
        bf16x2 kvr[4][4];
#pragma unroll
        for (int reg = 0; reg < 4; ++reg) {
            size_t gr = cbase + (size_t)nb[reg];
#pragma unroll
            for (int nt = 0; nt < 4; ++nt)
                kvr[reg][nt] = kv2[gr*CH + nt*16 + mlane];
        }
        float qv4[4];
#pragma unroll
        for (int nt = 0; nt < 4; ++nt)
            qv4[nt] = (float)qg[gp*CH + nt*16 + mlane];
#pragma unroll
        for (int nt = 0; nt < 4; ++nt) {
            int c = nt*16 + mlane;
            float vdf[4];
#pragma unroll
            for (int reg = 0; reg < 4; ++reg) {
                float dlt = acc[mt][nt][reg];
                float kvf = (float)kvr[reg][nt][0];
                float vv  = (float)kvr[reg][nt][1];
                int row = w*64 + mt*16 + kgrp*4 + reg;
                int off = row*CH + (((c >> 3) ^ (row & 7)) * 8) + (c & 7);
                At[off] = (bf16)(qv4[nt] - kvf + dlt);
                vdf[reg] = vv + dlt;
            }
            bf16x2 lo2; lo2[0] = (bf16)vdf[0]; lo2[1] = (bf16)vdf[1];
            bf16x2 hi2; hi2[0] = (bf16)vdf[2]; hi2[1] = (bf16)vdf[3];
            vdp[mt][nt][0] = lo2;
            vdp[mt][nt][1] = hi2;
        }
    }

    // ---- GEMM3: h2 = relu(a0 @ Wa1 + ba1) -> At ----
#pragma unroll
    for (int nt = 0; nt < 4; ++nt) {
        float b = ba1[nt*16 + mlane];
#pragma unroll
        for (int mt = 0; mt < 4; ++mt) { acc[mt][nt][0]=b; acc[mt][nt][1]=b; acc[mt][nt][2]=b; acc[mt][nt][3]=b; }
    }
    wave_gemm(At, acc, wpk + 512, w, lane);
#pragma unroll
    for (int mt = 0; mt < 4; ++mt) {
#pragma unroll
        for (int nt = 0; nt < 4; ++nt) {
            int c = nt*16 + mlane;
#pragma unroll
            for (int reg = 0; reg < 4; ++reg) {
                int row = w*64 + mt*16 + kgrp*4 + reg;
                int off = row*CH + (((c >> 3) ^ (row & 7)) * 8) + (c & 7);
                At[off] = (bf16)fmaxf(acc[mt][nt][reg], 0.f);
            }
        }
    }

    // ---- GEMM4: a = h2 @ Wa2 + ba2 ----
#pragma unroll
    for (int nt = 0; nt < 4; ++nt) {
        float b = ba2[nt*16 + mlane];
#pragma unroll
        for (int mt = 0; mt < 4; ++mt) { acc[mt][nt][0]=b; acc[mt][nt][1]=b; acc[mt][nt][2]=b; acc[mt][nt][3]=b; }
    }
    wave_gemm(At, acc, wpk + 1024, w, lane);

    // ---- softmax over K=16 + weighted sum (vd from registers) ----
#pragma unroll
    for (int mt = 0; mt < 4; ++mt) {
        size_t gp = p0 + (size_t)(w*4 + mt);
#pragma unroll
        for (int nt = 0; nt < 4; ++nt) {
            int c = nt*16 + mlane;
            float m = fmaxf(fmaxf(acc[mt][nt][0], acc[mt][nt][1]),
                            fmaxf(acc[mt][nt][2], acc[mt][nt][3]));
            m = fmaxf(m, __shfl_xor(m, 16));
            m = fmaxf(m, __shfl_xor(m, 32));
            float e[4], s = 0.f;
#pragma unroll
            for (int reg = 0; reg < 4; ++reg) { e[reg] = __expf(acc[mt][nt][reg] - m); s += e[reg]; }
            s += __shfl_xor(s, 16);
            s += __shfl_xor(s, 32);
            float num = 0.f;
            num += e[0] * (float)vdp[mt][nt][0][0];
            num += e[1] * (float)vdp[mt][nt][0][1];
            num += e[2] * (float)vdp[mt][nt][1][0];
            num += e[3] * (float)vdp[mt][nt][1][1];
            num += __shfl_xor(num, 16);
            num += __shfl_xor(num, 32);
            if (kgrp == 0) yout[gp*CH + c] = num / s;
        }
    }
}

// ---------------- Kernel 4: decode (C->F) + residual + passthrough tail ----------------
__global__ __launch_bounds__(256) void k_decode(
    const float* __restrict__ y, const float* __restrict__ Wd, const float* __restrict__ bd,
    const float* __restrict__ feat, const float* __restrict__ pos,
    const int* __restrict__ batch, float* __restrict__ out)
{
    int t = threadIdx.x;
    int f = t & 127, pl = t >> 7;
    size_t pt = (size_t)blockIdx.x * 2 + pl;
    const float* yr = y + pt*CH;
    float acc = bd[f] + feat[pt*FDIM + f];
#pragma unroll
    for (int c4 = 0; c4 < 16; ++c4) {
        float4 yv = *reinterpret_cast<const float4*>(yr + c4*4);
        acc += yv.x * Wd[(c4*4+0)*FDIM + f];
        acc += yv.y * Wd[(c4*4+1)*FDIM + f];
        acc += yv.z * Wd[(c4*4+2)*FDIM + f];
        acc += yv.w * Wd[(c4*4+3)*FDIM + f];
    }
    out[pt*FDIM + f] = acc;

    int i = blockIdx.x * 256 + t;
    if (i < NPTS*3) out[(size_t)NPTS*FDIM + i] = pos[i];
    if (i < NPTS)   out[(size_t)NPTS*FDIM + NPTS*3 + i] = (float)batch[i];
}

extern "C" void kernel_launch(void* const* d_in, const int* in_sizes, int n_in,
                              void* d_out, int out_size, void* d_ws, size_t ws_size,
                              hipStream_t stream)
{
    const float* feat  = (const float*)d_in[0];
    const float* pos   = (const float*)d_in[1];
    const int*   batch = (const int*)d_in[2];
    const float* Wenc  = (const float*)d_in[4];
    const float* benc  = (const float*)d_in[5];
    const float* Wq = (const float*)d_in[6];   const float* bq = (const float*)d_in[7];
    const float* Wk = (const float*)d_in[8];   const float* bk = (const float*)d_in[9];
    const float* Wv = (const float*)d_in[10];  const float* bv = (const float*)d_in[11];
    const float* Wp1= (const float*)d_in[12];  const float* bp1= (const float*)d_in[13];
    const float* Wp2= (const float*)d_in[14];  const float* bp2= (const float*)d_in[15];
    const float* Wa1= (const float*)d_in[16];  const float* ba1= (const float*)d_in[17];
    const float* Wa2= (const float*)d_in[18];  const float* ba2= (const float*)d_in[19];
    const float* Wd = (const float*)d_in[20];  const float* bd = (const float*)d_in[21];
    float* out = (float*)d_out;

    // ws layout: [idx 2MB][wsK 16MB -> reused: qb 4MB + kvb 8MB after merge]
    //            [yb 8MB][wpk 32KB][posW 512KB]
    char* W = (char*)d_ws;
    int*      idx = (int*)W;
    unsigned* wsK = (unsigned*)(W + (size_t)NPTS*KNN*4);
    bf16* qb  = (bf16*)wsK;
    bf16* kvb = qb + (size_t)NPTS*CH;
    float* yb = (float*)((char*)wsK + (size_t)NPTS*KNN*8*4);
    bf16*  wpk = (bf16*)(yb + (size_t)NPTS*CH);
    float4* posW = (float4*)((char*)wpk + 32768);

    k_prew<<<NPTS/256, 256, 0, stream>>>(pos, posW);
    k_knn<<<1024, 256, 0, stream>>>(posW, pos, wsK);
    k_merge<<<NPTS/64, 64, 0, stream>>>(wsK, idx, Wp2, Wa1, Wa2, wpk);

    // encode overwrites wsK region (qb/kvb) -- runs after merge consumed it
    k_encode<<<NPTS/4, 256, 0, stream>>>(feat, Wenc, benc, Wq, bq, Wk, bk, Wv, bv, qb, kvb);

    k_attn<<<NPTS/8, 128, 0, stream>>>(pos, idx, qb, kvb,
                                       Wp1, bp1, bp2, ba1, ba2, wpk, yb);

    k_decode<<<NPTS/2, 256, 0, stream>>>(yb, Wd, bd, feat, pos, batch, out);
}

// Round 16
// 401.889 us; speedup vs baseline: 1.0648x; 1.0648x over previous
//
#include <hip/hip_runtime.h>
#include <hip/hip_bf16.h>
#include <hip/hip_fp8.h>

#define NPTS 32768      // B*N
#define NPC  8192       // N per cloud
#define KNN  16
#define CH   64
#define FDIM 128
#define EMPTYKEY 0x7F7FFFFFu

typedef __bf16 bf16;
typedef unsigned short u16;
typedef __bf16 bf16x2 __attribute__((ext_vector_type(2)));
typedef __bf16 bf16x8 __attribute__((ext_vector_type(8)));
typedef float  f32x4  __attribute__((ext_vector_type(4)));

// ---------------- Kernel 1: encode (F->C) + q/k/v (C->C) ----------------
// q -> bf16; k,v -> fp8 e4m3 pair packed in one u16 per channel (halves the
// randomly-gathered row from 256B to 128B -> half the HBM transactions).
__global__ __launch_bounds__(256) void k_encode(
    const float* __restrict__ feat,
    const float* __restrict__ Wenc, const float* __restrict__ benc,
    const float* __restrict__ Wq, const float* __restrict__ bq,
    const float* __restrict__ Wk, const float* __restrict__ bk,
    const float* __restrict__ Wv, const float* __restrict__ bv,
    bf16* __restrict__ qo, u16* __restrict__ kvo)
{
    __shared__ float xs[4][CH];
    int t = threadIdx.x;
    int c = t & 63, pl = t >> 6;
    size_t pt = (size_t)blockIdx.x * 4 + pl;
    const float* fr = feat + pt * FDIM;
    float acc = benc[c];
#pragma unroll 8
    for (int f4 = 0; f4 < 32; ++f4) {
        float4 fv = *reinterpret_cast<const float4*>(fr + f4 * 4);
        acc += fv.x * Wenc[(f4*4+0)*CH + c];
        acc += fv.y * Wenc[(f4*4+1)*CH + c];
        acc += fv.z * Wenc[(f4*4+2)*CH + c];
        acc += fv.w * Wenc[(f4*4+3)*CH + c];
    }
    xs[pl][c] = acc;
    __syncthreads();
    float aq = bq[c], ak = bk[c], av = bv[c];
#pragma unroll 4
    for (int m = 0; m < CH; ++m) {
        float xm = xs[pl][m];
        aq += xm * Wq[m*CH + c];
        ak += xm * Wk[m*CH + c];
        av += xm * Wv[m*CH + c];
    }
    qo[pt*CH + c] = (bf16)aq;
    __hip_fp8_e4m3 k8(ak), v8(av);
    kvo[pt*CH + c] = (u16)k8.__x | ((u16)v8.__x << 8);
}

// ---------------- Kernel 2: exact kNN, slice-parallel, dot-form scan (R14) ----------------
// Candidates staged as (px,py,pz, w=-0.5|p|^2). Scan: s = p.q + w (3 fma);
// hit iff s >= sthr = (qq-thr)/2. d2 on hits only: d2 = max(qq-2s, 0).
// Groups of 8; buffer 21 slots, drain trigger 13.
__global__ __launch_bounds__(256, 4) void k_knn(
    const float* __restrict__ pos, unsigned* __restrict__ wsK)
{
    __shared__ float4 sp[1024];          // 16 KB slice (xyz + w)
    __shared__ unsigned sbuf[256 * 21];  // 21 KB append buffers

    int t = threadIdx.x;
    int blk = blockIdx.x;
    int slice = blk & 7;
    int qg = (blk >> 3) & 31;
    int cloud = blk >> 8;
    const float* pc = pos + (size_t)cloud * NPC * 3;
    int jbase = slice << 10;

    {
        const float4* src = reinterpret_cast<const float4*>(pc + (size_t)jbase * 3);
        float4 a = src[t*3+0], b1 = src[t*3+1], c1 = src[t*3+2];
        float px[4] = {a.x,  a.w,  b1.z, c1.y};
        float py[4] = {a.y,  b1.x, b1.w, c1.z};
        float pz[4] = {a.z,  b1.y, c1.x, c1.w};
#pragma unroll
        for (int i = 0; i < 4; ++i) {
            float w = -0.5f * fmaf(px[i], px[i], fmaf(py[i], py[i], pz[i]*pz[i]));
            sp[t*4+i] = make_float4(px[i], py[i], pz[i], w);
        }
    }
    __syncthreads();

    int qi = (qg << 8) + t;
    float myx = pc[qi*3+0], myy = pc[qi*3+1], myz = pc[qi*3+2];
    float qq = fmaf(myx, myx, fmaf(myy, myy, myz*myz));

    unsigned arr[16];
#pragma unroll
    for (int r = 0; r < 16; ++r) arr[r] = EMPTYKEY;
    float thrf = __uint_as_float(EMPTYKEY & 0xFFFFE000u);
    float sthr = (qq - thrf) * 0.5f;
    int cnt = 0;
    int base = t * 21;

    for (int g = 0; g < 1024; g += 8) {
        float sv[8];
#pragma unroll
        for (int u = 0; u < 8; ++u) {
            float4 p = sp[g + u];
            sv[u] = fmaf(myx, p.x, fmaf(myy, p.y, fmaf(myz, p.z, p.w)));
        }
        float m8 = fmaxf(fmaxf(fmaxf(sv[0], sv[1]), fmaxf(sv[2], sv[3])),
                         fmaxf(fmaxf(sv[4], sv[5]), fmaxf(sv[6], sv[7])));
        if (__any(m8 >= sthr)) {
#pragma unroll
            for (int u = 0; u < 8; ++u) {
                if (sv[u] >= sthr) {
                    float d2 = fmaxf(fmaf(-2.f, sv[u], qq), 0.f);
                    sbuf[base + cnt] = (__float_as_uint(d2) & 0xFFFFE000u)
                                       | (unsigned)(jbase + g + u);
                    ++cnt;
                }
            }
            if (__any(cnt >= 13)) {
#pragma unroll
                for (int b = 0; b < 20; ++b) {
                    unsigned key = (b < cnt) ? sbuf[base + b] : EMPTYKEY;
                    if (key < arr[15]) {
#pragma unroll
                        for (int r = 0; r < 16; ++r) {
                            unsigned lo = min(key, arr[r]);
                            unsigned hi = max(key, arr[r]);
                            arr[r] = lo; key = hi;
                        }
                    }
                }
                cnt = 0;
                thrf = __uint_as_float(arr[15] & 0xFFFFE000u);
                sthr = (qq - thrf) * 0.5f;
            }
        }
    }
#pragma unroll
    for (int b = 0; b < 20; ++b) {
        unsigned key = (b < cnt) ? sbuf[base + b] : EMPTYKEY;
        if (key < arr[15]) {
#pragma unroll
            for (int r = 0; r < 16; ++r) {
                unsigned lo = min(key, arr[r]);
                unsigned hi = max(key, arr[r]);
                arr[r] = lo; key = hi;
            }
        }
    }
    size_t gq = (size_t)cloud * NPC + qi;
#pragma unroll
    for (int r = 0; r < 16; ++r) wsK[(size_t)(slice*16 + r)*NPTS + gq] = arr[r];
}

// ---------------- Kernel 2b: merge 8 sorted 16-lists + pack weights ----------------
__global__ __launch_bounds__(64) void k_merge(
    const unsigned* __restrict__ wsK, int* __restrict__ idxout,
    const float* __restrict__ Wp2, const float* __restrict__ Wa1,
    const float* __restrict__ Wa2, bf16* __restrict__ wpk)
{
    __shared__ unsigned kk[64][137];   // 8 lists x (16 keys + sentinel)
    int t = threadIdx.x;
    size_t q = (size_t)blockIdx.x * 64 + t;
#pragma unroll
    for (int l = 0; l < 8; ++l) {
#pragma unroll
        for (int r = 0; r < 16; ++r)
            kk[t][l*17 + r] = wsK[(size_t)(l*16 + r)*NPTS + q];   // coalesced
        kk[t][l*17 + 16] = 0xFFFFFFFFu;
    }

    unsigned h0=0,h1=0,h2=0,h3=0,h4=0,h5=0,h6=0,h7=0;
    int* o = idxout + q * KNN;
    for (int r = 0; r < KNN; ++r) {
        unsigned best = 0xFFFFFFFFu; int bl = 0; unsigned k;
        k = kk[t][0*17 + h0]; if (k < best) { best = k; bl = 0; }
        k = kk[t][1*17 + h1]; if (k < best) { best = k; bl = 1; }
        k = kk[t][2*17 + h2]; if (k < best) { best = k; bl = 2; }
        k = kk[t][3*17 + h3]; if (k < best) { best = k; bl = 3; }
        k = kk[t][4*17 + h4]; if (k < best) { best = k; bl = 4; }
        k = kk[t][5*17 + h5]; if (k < best) { best = k; bl = 5; }
        k = kk[t][6*17 + h6]; if (k < best) { best = k; bl = 6; }
        k = kk[t][7*17 + h7]; if (k < best) { best = k; bl = 7; }
        o[r] = (int)(best & 0x1FFFu);
        h0 += (bl == 0); h1 += (bl == 1); h2 += (bl == 2); h3 += (bl == 3);
        h4 += (bl == 4); h5 += (bl == 5); h6 += (bl == 6); h7 += (bl == 7);
    }

    if (blockIdx.x == 0) {
        int lane = t;
        int mlane = lane & 15, kgrp = lane >> 4;
        const float* Ws[3] = {Wp2, Wa1, Wa2};
        bf16x8* ow = reinterpret_cast<bf16x8*>(wpk);
        for (int gmm = 0; gmm < 3; ++gmm) {
#pragma unroll
            for (int nt = 0; nt < 4; ++nt) {
#pragma unroll
                for (int kt = 0; kt < 2; ++kt) {
                    bf16x8 v;
#pragma unroll
                    for (int j = 0; j < 8; ++j)
                        v[j] = (bf16)Ws[gmm][(kt*32 + kgrp*8 + j)*CH + nt*16 + mlane];
                    ow[(gmm*8 + nt*2 + kt)*64 + lane] = v;
                }
            }
        }
    }
}

// ---------------- Kernel 3: MFMA fused neighbor MLPs + vector attention ----------------
__device__ __forceinline__ void wave_gemm(
    const bf16* At, f32x4 (&acc)[4][4], const bf16x8* __restrict__ wpk,
    int w, int lane)
{
    int kgrp = lane >> 4;
    bf16x8 wf[4][2];
#pragma unroll
    for (int nt = 0; nt < 4; ++nt)
#pragma unroll
        for (int kt = 0; kt < 2; ++kt)
            wf[nt][kt] = wpk[(nt*2 + kt)*64 + lane];
#pragma unroll
    for (int mt = 0; mt < 4; ++mt) {
        int row = w*64 + mt*16 + (lane & 15);
        const bf16* rb = At + row*CH;
        int sw = row & 7;
        bf16x8 a0 = *reinterpret_cast<const bf16x8*>(rb + ((kgrp     ^ sw) * 8));
        bf16x8 a1 = *reinterpret_cast<const bf16x8*>(rb + (((4+kgrp) ^ sw) * 8));
#pragma unroll
        for (int nt = 0; nt < 4; ++nt) {
            acc[mt][nt] = __builtin_amdgcn_mfma_f32_16x16x32_bf16(a0, wf[nt][0], acc[mt][nt], 0, 0, 0);
            acc[mt][nt] = __builtin_amdgcn_mfma_f32_16x16x32_bf16(a1, wf[nt][1], acc[mt][nt], 0, 0, 0);
        }
    }
}

// (128,6): occupancy ceiling (R11 win). kv gathered as fp8 pairs (u16/channel)
// -> half the 64B-segment transactions vs bf16 pairs. Batch all 16 kv loads
// per mt before dependent compute (R13).
__global__ __launch_bounds__(128, 6) void k_attn(
    const float* __restrict__ pos, const int* __restrict__ nidx,
    const bf16* __restrict__ qg, const u16* __restrict__ kvg,
    const float* __restrict__ Wp1, const float* __restrict__ bp1,
    const float* __restrict__ bp2, const float* __restrict__ ba1,
    const float* __restrict__ ba2, const bf16* __restrict__ wpkg,
    float* __restrict__ yout)
{
    __shared__ bf16 At[128 * CH];   // 16 KB (h1 -> a0 -> h2)

    int t = threadIdx.x;
    int w = t >> 6, lane = t & 63;
    int mlane = lane & 15, kgrp = lane >> 4;
    int blk = blockIdx.x;
    int xcd = blk & 7;
    int cloud = xcd >> 1;
    int sub = ((blk >> 3) << 1) | (xcd & 1);        // [0,1024) within cloud
    size_t cbase = (size_t)cloud * NPC;
    size_t p0 = cbase + (size_t)sub * 8;
    const bf16x8* wpk = reinterpret_cast<const bf16x8*>(wpkg);

    {
        int p = t >> 4, j = t & 15;
        size_t gp = p0 + p;
        int nbr = nidx[gp*KNN + j];
        size_t gn = cbase + (size_t)nbr;
        float rx = pos[gp*3+0] - pos[gn*3+0];
        float ry = pos[gp*3+1] - pos[gn*3+1];
        float rz = pos[gp*3+2] - pos[gn*3+2];
        float h[CH];
#pragma unroll
        for (int c4 = 0; c4 < 16; ++c4) {
            float4 w0 = *reinterpret_cast<const float4*>(Wp1 + 0*CH + c4*4);
            float4 w1 = *reinterpret_cast<const float4*>(Wp1 + 1*CH + c4*4);
            float4 w2 = *reinterpret_cast<const float4*>(Wp1 + 2*CH + c4*4);
            float4 bb = *reinterpret_cast<const float4*>(bp1 + c4*4);
            h[c4*4+0] = fmaxf(rx*w0.x + ry*w1.x + rz*w2.x + bb.x, 0.f);
            h[c4*4+1] = fmaxf(rx*w0.y + ry*w1.y + rz*w2.y + bb.y, 0.f);
            h[c4*4+2] = fmaxf(rx*w0.z + ry*w1.z + rz*w2.z + bb.z, 0.f);
            h[c4*4+3] = fmaxf(rx*w0.w + ry*w1.w + rz*w2.w + bb.w, 0.f);
        }
#pragma unroll
        for (int ch = 0; ch < 8; ++ch) {
            bf16x8 v;
#pragma unroll
            for (int e = 0; e < 8; ++e) v[e] = (bf16)h[ch*8 + e];
            *reinterpret_cast<bf16x8*>(&At[t*CH + (ch ^ (t & 7)) * 8]) = v;
        }
    }

    f32x4 acc[4][4];

    // ---- GEMM2: delta = h1 @ Wp2 + bp2 ----
#pragma unroll
    for (int nt = 0; nt < 4; ++nt) {
        float b = bp2[nt*16 + mlane];
#pragma unroll
        for (int mt = 0; mt < 4; ++mt) { acc[mt][nt][0]=b; acc[mt][nt][1]=b; acc[mt][nt][2]=b; acc[mt][nt][3]=b; }
    }
    wave_gemm(At, acc, wpk, w, lane);

    // ---- epilogue: a0 = q-k+delta -> At ; vd = v+delta -> packed regs ----
    bf16x2 vdp[4][4][2];
#pragma unroll
    for (int mt = 0; mt < 4; ++mt) {
        size_t gp = p0 + (size_t)(w*4 + mt);
        int nb[4];
#pragma unroll
        for (int reg = 0; reg < 4; ++reg)
            nb[reg] = nidx[gp*KNN + kgrp*4 + reg];
        // batch all 16 fp8-pair gathers for this mt before dependent compute
        u16 kvr[4][4];
#pragma unroll
        for (int reg = 0; reg < 4; ++reg) {
            size_t gr = cbase + (size_t)nb[reg];
#pragma unroll
            for (int nt = 0; nt < 4; ++nt)
                kvr[reg][nt] = kvg[gr*CH + nt*16 + mlane];
        }
        float qv4[4];
#pragma unroll
        for (int nt = 0; nt < 4; ++nt)
            qv4[nt] = (float)qg[gp*CH + nt*16 + mlane];
#pragma unroll
        for (int nt = 0; nt < 4; ++nt) {
            int c = nt*16 + mlane;
            float vdf[4];
#pragma unroll
            for (int reg = 0; reg < 4; ++reg) {
                float dlt = acc[mt][nt][reg];
                __hip_fp8_e4m3 k8, v8;
                k8.__x = (__hip_fp8_storage_t)(kvr[reg][nt] & 0xFF);
                v8.__x = (__hip_fp8_storage_t)(kvr[reg][nt] >> 8);
                float kvf = (float)k8;
                float vv  = (float)v8;
                int row = w*64 + mt*16 + kgrp*4 + reg;
                int off = row*CH + (((c >> 3) ^ (row & 7)) * 8) + (c & 7);
                At[off] = (bf16)(qv4[nt] - kvf + dlt);
                vdf[reg] = vv + dlt;
            }
            bf16x2 lo2; lo2[0] = (bf16)vdf[0]; lo2[1] = (bf16)vdf[1];
            bf16x2 hi2; hi2[0] = (bf16)vdf[2]; hi2[1] = (bf16)vdf[3];
            vdp[mt][nt][0] = lo2;
            vdp[mt][nt][1] = hi2;
        }
    }

    // ---- GEMM3: h2 = relu(a0 @ Wa1 + ba1) -> At ----
#pragma unroll
    for (int nt = 0; nt < 4; ++nt) {
        float b = ba1[nt*16 + mlane];
#pragma unroll
        for (int mt = 0; mt < 4; ++mt) { acc[mt][nt][0]=b; acc[mt][nt][1]=b; acc[mt][nt][2]=b; acc[mt][nt][3]=b; }
    }
    wave_gemm(At, acc, wpk + 512, w, lane);
#pragma unroll
    for (int mt = 0; mt < 4; ++mt) {
#pragma unroll
        for (int nt = 0; nt < 4; ++nt) {
            int c = nt*16 + mlane;
#pragma unroll
            for (int reg = 0; reg < 4; ++reg) {
                int row = w*64 + mt*16 + kgrp*4 + reg;
                int off = row*CH + (((c >> 3) ^ (row & 7)) * 8) + (c & 7);
                At[off] = (bf16)fmaxf(acc[mt][nt][reg], 0.f);
            }
        }
    }

    // ---- GEMM4: a = h2 @ Wa2 + ba2 ----
#pragma unroll
    for (int nt = 0; nt < 4; ++nt) {
        float b = ba2[nt*16 + mlane];
#pragma unroll
        for (int mt = 0; mt < 4; ++mt) { acc[mt][nt][0]=b; acc[mt][nt][1]=b; acc[mt][nt][2]=b; acc[mt][nt][3]=b; }
    }
    wave_gemm(At, acc, wpk + 1024, w, lane);

    // ---- softmax over K=16 + weighted sum (vd from registers) ----
#pragma unroll
    for (int mt = 0; mt < 4; ++mt) {
        size_t gp = p0 + (size_t)(w*4 + mt);
#pragma unroll
        for (int nt = 0; nt < 4; ++nt) {
            int c = nt*16 + mlane;
            float m = fmaxf(fmaxf(acc[mt][nt][0], acc[mt][nt][1]),
                            fmaxf(acc[mt][nt][2], acc[mt][nt][3]));
            m = fmaxf(m, __shfl_xor(m, 16));
            m = fmaxf(m, __shfl_xor(m, 32));
            float e[4], s = 0.f;
#pragma unroll
            for (int reg = 0; reg < 4; ++reg) { e[reg] = __expf(acc[mt][nt][reg] - m); s += e[reg]; }
            s += __shfl_xor(s, 16);
            s += __shfl_xor(s, 32);
            float num = 0.f;
            num += e[0] * (float)vdp[mt][nt][0][0];
            num += e[1] * (float)vdp[mt][nt][0][1];
            num += e[2] * (float)vdp[mt][nt][1][0];
            num += e[3] * (float)vdp[mt][nt][1][1];
            num += __shfl_xor(num, 16);
            num += __shfl_xor(num, 32);
            if (kgrp == 0) yout[gp*CH + c] = num / s;
        }
    }
}

// ---------------- Kernel 4: decode (C->F) + residual + passthrough tail ----------------
__global__ __launch_bounds__(256) void k_decode(
    const float* __restrict__ y, const float* __restrict__ Wd, const float* __restrict__ bd,
    const float* __restrict__ feat, const float* __restrict__ pos,
    const int* __restrict__ batch, float* __restrict__ out)
{
    int t = threadIdx.x;
    int f = t & 127, pl = t >> 7;
    size_t pt = (size_t)blockIdx.x * 2 + pl;
    const float* yr = y + pt*CH;
    float acc = bd[f] + feat[pt*FDIM + f];
#pragma unroll
    for (int c4 = 0; c4 < 16; ++c4) {
        float4 yv = *reinterpret_cast<const float4*>(yr + c4*4);
        acc += yv.x * Wd[(c4*4+0)*FDIM + f];
        acc += yv.y * Wd[(c4*4+1)*FDIM + f];
        acc += yv.z * Wd[(c4*4+2)*FDIM + f];
        acc += yv.w * Wd[(c4*4+3)*FDIM + f];
    }
    out[pt*FDIM + f] = acc;

    int i = blockIdx.x * 256 + t;
    if (i < NPTS*3) out[(size_t)NPTS*FDIM + i] = pos[i];
    if (i < NPTS)   out[(size_t)NPTS*FDIM + NPTS*3 + i] = (float)batch[i];
}

extern "C" void kernel_launch(void* const* d_in, const int* in_sizes, int n_in,
                              void* d_out, int out_size, void* d_ws, size_t ws_size,
                              hipStream_t stream)
{
    const float* feat  = (const float*)d_in[0];
    const float* pos   = (const float*)d_in[1];
    const int*   batch = (const int*)d_in[2];
    const float* Wenc  = (const float*)d_in[4];
    const float* benc  = (const float*)d_in[5];
    const float* Wq = (const float*)d_in[6];   const float* bq = (const float*)d_in[7];
    const float* Wk = (const float*)d_in[8];   const float* bk = (const float*)d_in[9];
    const float* Wv = (const float*)d_in[10];  const float* bv = (const float*)d_in[11];
    const float* Wp1= (const float*)d_in[12];  const float* bp1= (const float*)d_in[13];
    const float* Wp2= (const float*)d_in[14];  const float* bp2= (const float*)d_in[15];
    const float* Wa1= (const float*)d_in[16];  const float* ba1= (const float*)d_in[17];
    const float* Wa2= (const float*)d_in[18];  const float* ba2= (const float*)d_in[19];
    const float* Wd = (const float*)d_in[20];  const float* bd = (const float*)d_in[21];
    float* out = (float*)d_out;

    // ws layout: [idx 2MB][wsK 16MB -> reused: qb 4MB + kvb 4MB after merge][yb 8MB][wpk 32KB]
    char* W = (char*)d_ws;
    int*      idx = (int*)W;
    unsigned* wsK = (unsigned*)(W + (size_t)NPTS*KNN*4);
    bf16* qb  = (bf16*)wsK;
    u16*  kvb = (u16*)(qb + (size_t)NPTS*CH);
    float* yb = (float*)((char*)wsK + (size_t)NPTS*KNN*8*4);
    bf16*  wpk = (bf16*)(yb + (size_t)NPTS*CH);

    k_knn<<<1024, 256, 0, stream>>>(pos, wsK);
    k_merge<<<NPTS/64, 64, 0, stream>>>(wsK, idx, Wp2, Wa1, Wa2, wpk);

    // encode overwrites wsK region (qb/kvb) -- runs after merge consumed it
    k_encode<<<NPTS/4, 256, 0, stream>>>(feat, Wenc, benc, Wq, bq, Wk, bk, Wv, bv, qb, kvb);

    k_attn<<<NPTS/8, 128, 0, stream>>>(pos, idx, qb, kvb,
                                       Wp1, bp1, bp2, ba1, ba2, wpk, yb);

    k_decode<<<NPTS/2, 256, 0, stream>>>(yb, Wd, bd, feat, pos, batch, out);
}

// Round 17
// 381.215 us; speedup vs baseline: 1.1225x; 1.0542x over previous
//
#include <hip/hip_runtime.h>
#include <hip/hip_bf16.h>
#include <hip/hip_fp8.h>

#define NPTS 32768      // B*N
#define NPC  8192       // N per cloud
#define KNN  16
#define CH   64
#define FDIM 128
#define EMPTYKEY 0x7F7FFFFFu

typedef __bf16 bf16;
typedef unsigned short u16;
typedef __bf16 bf16x2 __attribute__((ext_vector_type(2)));
typedef __bf16 bf16x8 __attribute__((ext_vector_type(8)));
typedef float  f32x4  __attribute__((ext_vector_type(4)));

__device__ __forceinline__ unsigned med3u(unsigned a, unsigned b, unsigned c) {
    unsigned d;
    asm("v_med3_u32 %0, %1, %2, %3" : "=v"(d) : "v"(a), "v"(b), "v"(c));
    return d;
}

// sorted-insert of key into ascending arr[16], dropping arr[15].
// new[r] = med3(key, arr[r], arr[r-1]); new[0] = min(key, arr[0]).
// 17 ops, all levels independent (reads old values only).
__device__ __forceinline__ void sorted_insert(unsigned (&arr)[16], unsigned key) {
    unsigned na[16];
    na[0] = min(key, arr[0]);
#pragma unroll
    for (int r = 1; r < 16; ++r) na[r] = med3u(key, arr[r], arr[r-1]);
#pragma unroll
    for (int r = 0; r < 16; ++r) arr[r] = na[r];
}

// ---------------- Kernel 1: encode (F->C) + q/k/v (C->C) ----------------
// q -> bf16; k,v -> fp8 e4m3 pair packed in one u16 per channel.
__global__ __launch_bounds__(256) void k_encode(
    const float* __restrict__ feat,
    const float* __restrict__ Wenc, const float* __restrict__ benc,
    const float* __restrict__ Wq, const float* __restrict__ bq,
    const float* __restrict__ Wk, const float* __restrict__ bk,
    const float* __restrict__ Wv, const float* __restrict__ bv,
    bf16* __restrict__ qo, u16* __restrict__ kvo)
{
    __shared__ float xs[4][CH];
    int t = threadIdx.x;
    int c = t & 63, pl = t >> 6;
    size_t pt = (size_t)blockIdx.x * 4 + pl;
    const float* fr = feat + pt * FDIM;
    float acc = benc[c];
#pragma unroll 8
    for (int f4 = 0; f4 < 32; ++f4) {
        float4 fv = *reinterpret_cast<const float4*>(fr + f4 * 4);
        acc += fv.x * Wenc[(f4*4+0)*CH + c];
        acc += fv.y * Wenc[(f4*4+1)*CH + c];
        acc += fv.z * Wenc[(f4*4+2)*CH + c];
        acc += fv.w * Wenc[(f4*4+3)*CH + c];
    }
    xs[pl][c] = acc;
    __syncthreads();
    float aq = bq[c], ak = bk[c], av = bv[c];
#pragma unroll 4
    for (int m = 0; m < CH; ++m) {
        float xm = xs[pl][m];
        aq += xm * Wq[m*CH + c];
        ak += xm * Wk[m*CH + c];
        av += xm * Wv[m*CH + c];
    }
    qo[pt*CH + c] = (bf16)aq;
    __hip_fp8_e4m3 k8(ak), v8(av);
    kvo[pt*CH + c] = (u16)k8.__x | ((u16)v8.__x << 8);
}

// ---------------- Kernel 2: exact kNN, slice-parallel, dot-form scan ----------------
// Candidates staged as (px,py,pz, w=-0.5|p|^2). Scan: s = p.q + w (3 fma);
// hit iff s >= sthr = (qq-thr)/2. d2 on hits only: d2 = max(qq-2s, 0).
// Groups of 8; buffer 21 slots, drain trigger 13. Drain insert via
// v_med3_u32 sorted-insert (16 parallel ops vs 32 serial min/max).
__global__ __launch_bounds__(256, 4) void k_knn(
    const float* __restrict__ pos, unsigned* __restrict__ wsK)
{
    __shared__ float4 sp[1024];          // 16 KB slice (xyz + w)
    __shared__ unsigned sbuf[256 * 21];  // 21 KB append buffers

    int t = threadIdx.x;
    int blk = blockIdx.x;
    int slice = blk & 7;
    int qg = (blk >> 3) & 31;
    int cloud = blk >> 8;
    const float* pc = pos + (size_t)cloud * NPC * 3;
    int jbase = slice << 10;

    {
        const float4* src = reinterpret_cast<const float4*>(pc + (size_t)jbase * 3);
        float4 a = src[t*3+0], b1 = src[t*3+1], c1 = src[t*3+2];
        float px[4] = {a.x,  a.w,  b1.z, c1.y};
        float py[4] = {a.y,  b1.x, b1.w, c1.z};
        float pz[4] = {a.z,  b1.y, c1.x, c1.w};
#pragma unroll
        for (int i = 0; i < 4; ++i) {
            float w = -0.5f * fmaf(px[i], px[i], fmaf(py[i], py[i], pz[i]*pz[i]));
            sp[t*4+i] = make_float4(px[i], py[i], pz[i], w);
        }
    }
    __syncthreads();

    int qi = (qg << 8) + t;
    float myx = pc[qi*3+0], myy = pc[qi*3+1], myz = pc[qi*3+2];
    float qq = fmaf(myx, myx, fmaf(myy, myy, myz*myz));

    unsigned arr[16];
#pragma unroll
    for (int r = 0; r < 16; ++r) arr[r] = EMPTYKEY;
    float thrf = __uint_as_float(EMPTYKEY & 0xFFFFE000u);
    float sthr = (qq - thrf) * 0.5f;
    int cnt = 0;
    int base = t * 21;

    for (int g = 0; g < 1024; g += 8) {
        float sv[8];
#pragma unroll
        for (int u = 0; u < 8; ++u) {
            float4 p = sp[g + u];
            sv[u] = fmaf(myx, p.x, fmaf(myy, p.y, fmaf(myz, p.z, p.w)));
        }
        float m8 = fmaxf(fmaxf(fmaxf(sv[0], sv[1]), fmaxf(sv[2], sv[3])),
                         fmaxf(fmaxf(sv[4], sv[5]), fmaxf(sv[6], sv[7])));
        if (__any(m8 >= sthr)) {
#pragma unroll
            for (int u = 0; u < 8; ++u) {
                if (sv[u] >= sthr) {
                    float d2 = fmaxf(fmaf(-2.f, sv[u], qq), 0.f);
                    sbuf[base + cnt] = (__float_as_uint(d2) & 0xFFFFE000u)
                                       | (unsigned)(jbase + g + u);
                    ++cnt;
                }
            }
            if (__any(cnt >= 13)) {
#pragma unroll
                for (int b = 0; b < 20; ++b) {
                    unsigned key = (b < cnt) ? sbuf[base + b] : EMPTYKEY;
                    if (key < arr[15]) sorted_insert(arr, key);
                }
                cnt = 0;
                thrf = __uint_as_float(arr[15] & 0xFFFFE000u);
                sthr = (qq - thrf) * 0.5f;
            }
        }
    }
#pragma unroll
    for (int b = 0; b < 20; ++b) {
        unsigned key = (b < cnt) ? sbuf[base + b] : EMPTYKEY;
        if (key < arr[15]) sorted_insert(arr, key);
    }
    size_t gq = (size_t)cloud * NPC + qi;
#pragma unroll
    for (int r = 0; r < 16; ++r) wsK[(size_t)(slice*16 + r)*NPTS + gq] = arr[r];
}

// ---------------- Kernel 2b: merge 8 sorted 16-lists + pack weights ----------------
__global__ __launch_bounds__(64) void k_merge(
    const unsigned* __restrict__ wsK, int* __restrict__ idxout,
    const float* __restrict__ Wp2, const float* __restrict__ Wa1,
    const float* __restrict__ Wa2, bf16* __restrict__ wpk)
{
    __shared__ unsigned kk[64][137];   // 8 lists x (16 keys + sentinel)
    int t = threadIdx.x;
    size_t q = (size_t)blockIdx.x * 64 + t;
#pragma unroll
    for (int l = 0; l < 8; ++l) {
#pragma unroll
        for (int r = 0; r < 16; ++r)
            kk[t][l*17 + r] = wsK[(size_t)(l*16 + r)*NPTS + q];   // coalesced
        kk[t][l*17 + 16] = 0xFFFFFFFFu;
    }

    unsigned h0=0,h1=0,h2=0,h3=0,h4=0,h5=0,h6=0,h7=0;
    int* o = idxout + q * KNN;
    for (int r = 0; r < KNN; ++r) {
        unsigned best = 0xFFFFFFFFu; int bl = 0; unsigned k;
        k = kk[t][0*17 + h0]; if (k < best) { best = k; bl = 0; }
        k = kk[t][1*17 + h1]; if (k < best) { best = k; bl = 1; }
        k = kk[t][2*17 + h2]; if (k < best) { best = k; bl = 2; }
        k = kk[t][3*17 + h3]; if (k < best) { best = k; bl = 3; }
        k = kk[t][4*17 + h4]; if (k < best) { best = k; bl = 4; }
        k = kk[t][5*17 + h5]; if (k < best) { best = k; bl = 5; }
        k = kk[t][6*17 + h6]; if (k < best) { best = k; bl = 6; }
        k = kk[t][7*17 + h7]; if (k < best) { best = k; bl = 7; }
        o[r] = (int)(best & 0x1FFFu);
        h0 += (bl == 0); h1 += (bl == 1); h2 += (bl == 2); h3 += (bl == 3);
        h4 += (bl == 4); h5 += (bl == 5); h6 += (bl == 6); h7 += (bl == 7);
    }

    if (blockIdx.x == 0) {
        int lane = t;
        int mlane = lane & 15, kgrp = lane >> 4;
        const float* Ws[3] = {Wp2, Wa1, Wa2};
        bf16x8* ow = reinterpret_cast<bf16x8*>(wpk);
        for (int gmm = 0; gmm < 3; ++gmm) {
#pragma unroll
            for (int nt = 0; nt < 4; ++nt) {
#pragma unroll
                for (int kt = 0; kt < 2; ++kt) {
                    bf16x8 v;
#pragma unroll
                    for (int j = 0; j < 8; ++j)
                        v[j] = (bf16)Ws[gmm][(kt*32 + kgrp*8 + j)*CH + nt*16 + mlane];
                    ow[(gmm*8 + nt*2 + kt)*64 + lane] = v;
                }
            }
        }
    }
}

// ---------------- Kernel 3: MFMA fused neighbor MLPs + vector attention ----------------
__device__ __forceinline__ void wave_gemm(
    const bf16* At, f32x4 (&acc)[4][4], const bf16x8* __restrict__ wpk,
    int w, int lane)
{
    int kgrp = lane >> 4;
    bf16x8 wf[4][2];
#pragma unroll
    for (int nt = 0; nt < 4; ++nt)
#pragma unroll
        for (int kt = 0; kt < 2; ++kt)
            wf[nt][kt] = wpk[(nt*2 + kt)*64 + lane];
#pragma unroll
    for (int mt = 0; mt < 4; ++mt) {
        int row = w*64 + mt*16 + (lane & 15);
        const bf16* rb = At + row*CH;
        int sw = row & 7;
        bf16x8 a0 = *reinterpret_cast<const bf16x8*>(rb + ((kgrp     ^ sw) * 8));
        bf16x8 a1 = *reinterpret_cast<const bf16x8*>(rb + (((4+kgrp) ^ sw) * 8));
#pragma unroll
        for (int nt = 0; nt < 4; ++nt) {
            acc[mt][nt] = __builtin_amdgcn_mfma_f32_16x16x32_bf16(a0, wf[nt][0], acc[mt][nt], 0, 0, 0);
            acc[mt][nt] = __builtin_amdgcn_mfma_f32_16x16x32_bf16(a1, wf[nt][1], acc[mt][nt], 0, 0, 0);
        }
    }
}

// (128,6): occupancy ceiling (R11 win). fp8 kv pairs; batched gathers (R13).
__global__ __launch_bounds__(128, 6) void k_attn(
    const float* __restrict__ pos, const int* __restrict__ nidx,
    const bf16* __restrict__ qg, const u16* __restrict__ kvg,
    const float* __restrict__ Wp1, const float* __restrict__ bp1,
    const float* __restrict__ bp2, const float* __restrict__ ba1,
    const float* __restrict__ ba2, const bf16* __restrict__ wpkg,
    float* __restrict__ yout)
{
    __shared__ bf16 At[128 * CH];   // 16 KB (h1 -> a0 -> h2)

    int t = threadIdx.x;
    int w = t >> 6, lane = t & 63;
    int mlane = lane & 15, kgrp = lane >> 4;
    int blk = blockIdx.x;
    int xcd = blk & 7;
    int cloud = xcd >> 1;
    int sub = ((blk >> 3) << 1) | (xcd & 1);        // [0,1024) within cloud
    size_t cbase = (size_t)cloud * NPC;
    size_t p0 = cbase + (size_t)sub * 8;
    const bf16x8* wpk = reinterpret_cast<const bf16x8*>(wpkg);

    {
        int p = t >> 4, j = t & 15;
        size_t gp = p0 + p;
        int nbr = nidx[gp*KNN + j];
        size_t gn = cbase + (size_t)nbr;
        float rx = pos[gp*3+0] - pos[gn*3+0];
        float ry = pos[gp*3+1] - pos[gn*3+1];
        float rz = pos[gp*3+2] - pos[gn*3+2];
        float h[CH];
#pragma unroll
        for (int c4 = 0; c4 < 16; ++c4) {
            float4 w0 = *reinterpret_cast<const float4*>(Wp1 + 0*CH + c4*4);
            float4 w1 = *reinterpret_cast<const float4*>(Wp1 + 1*CH + c4*4);
            float4 w2 = *reinterpret_cast<const float4*>(Wp1 + 2*CH + c4*4);
            float4 bb = *reinterpret_cast<const float4*>(bp1 + c4*4);
            h[c4*4+0] = fmaxf(rx*w0.x + ry*w1.x + rz*w2.x + bb.x, 0.f);
            h[c4*4+1] = fmaxf(rx*w0.y + ry*w1.y + rz*w2.y + bb.y, 0.f);
            h[c4*4+2] = fmaxf(rx*w0.z + ry*w1.z + rz*w2.z + bb.z, 0.f);
            h[c4*4+3] = fmaxf(rx*w0.w + ry*w1.w + rz*w2.w + bb.w, 0.f);
        }
#pragma unroll
        for (int ch = 0; ch < 8; ++ch) {
            bf16x8 v;
#pragma unroll
            for (int e = 0; e < 8; ++e) v[e] = (bf16)h[ch*8 + e];
            *reinterpret_cast<bf16x8*>(&At[t*CH + (ch ^ (t & 7)) * 8]) = v;
        }
    }

    f32x4 acc[4][4];

    // ---- GEMM2: delta = h1 @ Wp2 + bp2 ----
#pragma unroll
    for (int nt = 0; nt < 4; ++nt) {
        float b = bp2[nt*16 + mlane];
#pragma unroll
        for (int mt = 0; mt < 4; ++mt) { acc[mt][nt][0]=b; acc[mt][nt][1]=b; acc[mt][nt][2]=b; acc[mt][nt][3]=b; }
    }
    wave_gemm(At, acc, wpk, w, lane);

    // ---- epilogue: a0 = q-k+delta -> At ; vd = v+delta -> packed regs ----
    bf16x2 vdp[4][4][2];
#pragma unroll
    for (int mt = 0; mt < 4; ++mt) {
        size_t gp = p0 + (size_t)(w*4 + mt);
        int nb[4];
#pragma unroll
        for (int reg = 0; reg < 4; ++reg)
            nb[reg] = nidx[gp*KNN + kgrp*4 + reg];
        u16 kvr[4][4];
#pragma unroll
        for (int reg = 0; reg < 4; ++reg) {
            size_t gr = cbase + (size_t)nb[reg];
#pragma unroll
            for (int nt = 0; nt < 4; ++nt)
                kvr[reg][nt] = kvg[gr*CH + nt*16 + mlane];
        }
        float qv4[4];
#pragma unroll
        for (int nt = 0; nt < 4; ++nt)
            qv4[nt] = (float)qg[gp*CH + nt*16 + mlane];
#pragma unroll
        for (int nt = 0; nt < 4; ++nt) {
            int c = nt*16 + mlane;
            float vdf[4];
#pragma unroll
            for (int reg = 0; reg < 4; ++reg) {
                float dlt = acc[mt][nt][reg];
                __hip_fp8_e4m3 k8, v8;
                k8.__x = (__hip_fp8_storage_t)(kvr[reg][nt] & 0xFF);
                v8.__x = (__hip_fp8_storage_t)(kvr[reg][nt] >> 8);
                float kvf = (float)k8;
                float vv  = (float)v8;
                int row = w*64 + mt*16 + kgrp*4 + reg;
                int off = row*CH + (((c >> 3) ^ (row & 7)) * 8) + (c & 7);
                At[off] = (bf16)(qv4[nt] - kvf + dlt);
                vdf[reg] = vv + dlt;
            }
            bf16x2 lo2; lo2[0] = (bf16)vdf[0]; lo2[1] = (bf16)vdf[1];
            bf16x2 hi2; hi2[0] = (bf16)vdf[2]; hi2[1] = (bf16)vdf[3];
            vdp[mt][nt][0] = lo2;
            vdp[mt][nt][1] = hi2;
        }
    }

    // ---- GEMM3: h2 = relu(a0 @ Wa1 + ba1) -> At ----
#pragma unroll
    for (int nt = 0; nt < 4; ++nt) {
        float b = ba1[nt*16 + mlane];
#pragma unroll
        for (int mt = 0; mt < 4; ++mt) { acc[mt][nt][0]=b; acc[mt][nt][1]=b; acc[mt][nt][2]=b; acc[mt][nt][3]=b; }
    }
    wave_gemm(At, acc, wpk + 512, w, lane);
#pragma unroll
    for (int mt = 0; mt < 4; ++mt) {
#pragma unroll
        for (int nt = 0; nt < 4; ++nt) {
            int c = nt*16 + mlane;
#pragma unroll
            for (int reg = 0; reg < 4; ++reg) {
                int row = w*64 + mt*16 + kgrp*4 + reg;
                int off = row*CH + (((c >> 3) ^ (row & 7)) * 8) + (c & 7);
                At[off] = (bf16)fmaxf(acc[mt][nt][reg], 0.f);
            }
        }
    }

    // ---- GEMM4: a = h2 @ Wa2 + ba2 ----
#pragma unroll
    for (int nt = 0; nt < 4; ++nt) {
        float b = ba2[nt*16 + mlane];
#pragma unroll
        for (int mt = 0; mt < 4; ++mt) { acc[mt][nt][0]=b; acc[mt][nt][1]=b; acc[mt][nt][2]=b; acc[mt][nt][3]=b; }
    }
    wave_gemm(At, acc, wpk + 1024, w, lane);

    // ---- softmax over K=16 + weighted sum (vd from registers) ----
#pragma unroll
    for (int mt = 0; mt < 4; ++mt) {
        size_t gp = p0 + (size_t)(w*4 + mt);
#pragma unroll
        for (int nt = 0; nt < 4; ++nt) {
            int c = nt*16 + mlane;
            float m = fmaxf(fmaxf(acc[mt][nt][0], acc[mt][nt][1]),
                            fmaxf(acc[mt][nt][2], acc[mt][nt][3]));
            m = fmaxf(m, __shfl_xor(m, 16));
            m = fmaxf(m, __shfl_xor(m, 32));
            float e[4], s = 0.f;
#pragma unroll
            for (int reg = 0; reg < 4; ++reg) { e[reg] = __expf(acc[mt][nt][reg] - m); s += e[reg]; }
            s += __shfl_xor(s, 16);
            s += __shfl_xor(s, 32);
            float num = 0.f;
            num += e[0] * (float)vdp[mt][nt][0][0];
            num += e[1] * (float)vdp[mt][nt][0][1];
            num += e[2] * (float)vdp[mt][nt][1][0];
            num += e[3] * (float)vdp[mt][nt][1][1];
            num += __shfl_xor(num, 16);
            num += __shfl_xor(num, 32);
            if (kgrp == 0) yout[gp*CH + c] = num / s;
        }
    }
}

// ---------------- Kernel 4: decode (C->F) + residual + passthrough tail ----------------
__global__ __launch_bounds__(256) void k_decode(
    const float* __restrict__ y, const float* __restrict__ Wd, const float* __restrict__ bd,
    const float* __restrict__ feat, const float* __restrict__ pos,
    const int* __restrict__ batch, float* __restrict__ out)
{
    int t = threadIdx.x;
    int f = t & 127, pl = t >> 7;
    size_t pt = (size_t)blockIdx.x * 2 + pl;
    const float* yr = y + pt*CH;
    float acc = bd[f] + feat[pt*FDIM + f];
#pragma unroll
    for (int c4 = 0; c4 < 16; ++c4) {
        float4 yv = *reinterpret_cast<const float4*>(yr + c4*4);
        acc += yv.x * Wd[(c4*4+0)*FDIM + f];
        acc += yv.y * Wd[(c4*4+1)*FDIM + f];
        acc += yv.z * Wd[(c4*4+2)*FDIM + f];
        acc += yv.w * Wd[(c4*4+3)*FDIM + f];
    }
    out[pt*FDIM + f] = acc;

    int i = blockIdx.x * 256 + t;
    if (i < NPTS*3) out[(size_t)NPTS*FDIM + i] = pos[i];
    if (i < NPTS)   out[(size_t)NPTS*FDIM + NPTS*3 + i] = (float)batch[i];
}

extern "C" void kernel_launch(void* const* d_in, const int* in_sizes, int n_in,
                              void* d_out, int out_size, void* d_ws, size_t ws_size,
                              hipStream_t stream)
{
    const float* feat  = (const float*)d_in[0];
    const float* pos   = (const float*)d_in[1];
    const int*   batch = (const int*)d_in[2];
    const float* Wenc  = (const float*)d_in[4];
    const float* benc  = (const float*)d_in[5];
    const float* Wq = (const float*)d_in[6];   const float* bq = (const float*)d_in[7];
    const float* Wk = (const float*)d_in[8];   const float* bk = (const float*)d_in[9];
    const float* Wv = (const float*)d_in[10];  const float* bv = (const float*)d_in[11];
    const float* Wp1= (const float*)d_in[12];  const float* bp1= (const float*)d_in[13];
    const float* Wp2= (const float*)d_in[14];  const float* bp2= (const float*)d_in[15];
    const float* Wa1= (const float*)d_in[16];  const float* ba1= (const float*)d_in[17];
    const float* Wa2= (const float*)d_in[18];  const float* ba2= (const float*)d_in[19];
    const float* Wd = (const float*)d_in[20];  const float* bd = (const float*)d_in[21];
    float* out = (float*)d_out;

    // ws layout: [idx 2MB][wsK 16MB -> reused: qb 4MB + kvb 4MB after merge][yb 8MB][wpk 32KB]
    char* W = (char*)d_ws;
    int*      idx = (int*)W;
    unsigned* wsK = (unsigned*)(W + (size_t)NPTS*KNN*4);
    bf16* qb  = (bf16*)wsK;
    u16*  kvb = (u16*)(qb + (size_t)NPTS*CH);
    float* yb = (float*)((char*)wsK + (size_t)NPTS*KNN*8*4);
    bf16*  wpk = (bf16*)(yb + (size_t)NPTS*CH);

    k_knn<<<1024, 256, 0, stream>>>(pos, wsK);
    k_merge<<<NPTS/64, 64, 0, stream>>>(wsK, idx, Wp2, Wa1, Wa2, wpk);

    // encode overwrites wsK region (qb/kvb) -- runs after merge consumed it
    k_encode<<<NPTS/4, 256, 0, stream>>>(feat, Wenc, benc, Wq, bq, Wk, bk, Wv, bv, qb, kvb);

    k_attn<<<NPTS/8, 128, 0, stream>>>(pos, idx, qb, kvb,
                                       Wp1, bp1, bp2, ba1, ba2, wpk, yb);

    k_decode<<<NPTS/2, 256, 0, stream>>>(yb, Wd, bd, feat, pos, batch, out);
}